// Round 1
// baseline (8069.289 us; speedup 1.0000x reference)
//
#include <hip/hip_runtime.h>
#include <hip/hip_bf16.h>
#include <math.h>

#define TS   256
#define CTS  512
#define MB   64
#define D    512
#define KMIX 20

// d_out layout (floats): hiddens [TS][MB][D], att_k [TS][MB][KMIX], att_w [TS][MB][D]
#define HID_SIZE  (TS*MB*D)          // 8388608
#define ATTK_OFF  (HID_SIZE)
#define ATTK_SIZE (TS*MB*KMIX)       // 327680
#define ATTW_OFF  (HID_SIZE + ATTK_SIZE)

// ws layout (bytes):
//  WrT  (bf16 512x512, transposed reset half of Wur) @ 0        (524288)
//  UT   (bf16 512x512, transposed U)                 @ 524288   (524288)
//  alpha(f32 TS*MB*K)                                @ 1048576  (1310720)
//  beta                                              @ 2359296  (1310720)
//  kinc                                              @ 3670016  (1310720)
//  X    (f32 TS*MB*D)                                @ 5242880  (33554432)
//  F2   (f32 TS*MB*1024: [0:512]=state, [512:1024]=gate_r) @ 38797312 (67108864)
// total required: 105906176 bytes (~101 MiB)
#define WS_WRT   0
#define WS_UT    524288
#define WS_ALPHA 1048576
#define WS_BETA  2359296
#define WS_KINC  3670016
#define WS_X     5242880
#define WS_F2    38797312

__device__ __forceinline__ float bflo(unsigned u) { return __uint_as_float(u << 16); }
__device__ __forceinline__ float bfhi(unsigned u) { return __uint_as_float(u & 0xffff0000u); }

__device__ __forceinline__ unsigned short f2bf(float v) {
  __hip_bfloat16 h = __float2bfloat16(v);
  union { __hip_bfloat16 h; unsigned short u; } cvt; cvt.h = h;
  return cvt.u;
}

// ---------------- K0: transpose + bf16-cast recurrence weights ----------------
// WrT[j][i] = Wur[i][512+j] ; UT[j][i] = U[i][j]
__global__ __launch_bounds__(256) void prep_weights(const float* __restrict__ Wur,
                                                    const float* __restrict__ U,
                                                    unsigned short* __restrict__ WrT,
                                                    unsigned short* __restrict__ UT) {
  int idx = blockIdx.x * 256 + threadIdx.x;   // 512*512
  int j = idx >> 9, i = idx & 511;
  WrT[idx] = f2bf(Wur[i * 1024 + 512 + j]);
  UT[idx]  = f2bf(U[i * 512 + j]);
}

// ---------------- K1: alpha = inp@Wa+ba (log domain), beta = exp(inp@Wb+bb), kinc = exp(inp@Wk+bk)
#define ABK_ROWS 8
__global__ __launch_bounds__(64) void abk_kernel(const float* __restrict__ inp,
                                                 const float* __restrict__ Wa, const float* __restrict__ ba,
                                                 const float* __restrict__ Wb, const float* __restrict__ bb_,
                                                 const float* __restrict__ Wk, const float* __restrict__ bk,
                                                 float* __restrict__ alpha, float* __restrict__ beta,
                                                 float* __restrict__ kinc) {
  __shared__ float rows[ABK_ROWS][D];
  int tb0 = blockIdx.x * ABK_ROWS;
  for (int x = threadIdx.x; x < ABK_ROWS * D; x += 64)
    rows[x >> 9][x & 511] = inp[(size_t)tb0 * D + x];
  __syncthreads();
  int j = threadIdx.x;
  if (j >= 3 * KMIX) return;
  int wj = j % KMIX;
  int which = j / KMIX;
  const float* W = (which == 0) ? Wa : ((which == 1) ? Wb : Wk);
  const float* B = (which == 0) ? ba : ((which == 1) ? bb_ : bk);
  float acc[ABK_ROWS];
  float bias = B[wj];
#pragma unroll
  for (int r = 0; r < ABK_ROWS; r++) acc[r] = bias;
  for (int i = 0; i < D; i++) {
    float wv = W[i * KMIX + wj];
#pragma unroll
    for (int r = 0; r < ABK_ROWS; r++) acc[r] += rows[r][i] * wv;
  }
  for (int r = 0; r < ABK_ROWS; r++) {
    int tb = tb0 + r;
    float v = acc[r];
    if (which == 0) alpha[tb * KMIX + wj] = v;
    else if (which == 1) beta[tb * KMIX + wj] = expf(v);
    else kinc[tb * KMIX + wj] = expf(v);
  }
}

// ---------------- K2: k cumsum over t; writes att_k region of d_out ----------------
__global__ __launch_bounds__(256) void cumsum_kernel(const float* __restrict__ att_init,
                                                     const float* __restrict__ kinc,
                                                     float* __restrict__ kout) {
  int idx = blockIdx.x * 256 + threadIdx.x;   // MB*KMIX = 1280
  if (idx >= MB * KMIX) return;
  float k = att_init[idx];
  for (int t = 0; t < TS; t++) {
    k += kinc[t * MB * KMIX + idx];
    kout[t * MB * KMIX + idx] = k;
  }
}

// ---------------- K3: phi + w GEMM; writes att_w region of d_out ----------------
#define WT 8
__global__ __launch_bounds__(512) void phi_w_kernel(const float* __restrict__ c_inp,
                                                    const float* __restrict__ alpha,
                                                    const float* __restrict__ beta,
                                                    const float* __restrict__ katt,
                                                    float* __restrict__ wout) {
  int b  = blockIdx.x / (TS / WT);
  int t0 = (blockIdx.x % (TS / WT)) * WT;
  __shared__ float phi[WT][CTS];
  __shared__ float pa[WT][KMIX], pb[WT][KMIX], pk[WT][KMIX];
  for (int x = threadIdx.x; x < WT * KMIX; x += 512) {
    int tt = x / KMIX, j = x % KMIX;
    int tb = (t0 + tt) * MB + b;
    pa[tt][j] = alpha[tb * KMIX + j];
    pb[tt][j] = beta[tb * KMIX + j];
    pk[tt][j] = katt[tb * KMIX + j];
  }
  __syncthreads();
  {
    int c = threadIdx.x;
    float fc = (float)c;
#pragma unroll
    for (int tt = 0; tt < WT; tt++) {
      float s = 0.f;
#pragma unroll
      for (int j = 0; j < KMIX; j++) {
        float dd = pk[tt][j] - fc;
        s += expf(pa[tt][j] - pb[tt][j] * dd * dd);
      }
      phi[tt][c] = s;
    }
  }
  __syncthreads();
  {
    int d = threadIdx.x;
    float acc[WT];
#pragma unroll
    for (int tt = 0; tt < WT; tt++) acc[tt] = 0.f;
    const float* cb = c_inp + (size_t)b * D + d;
    for (int c2 = 0; c2 < CTS; c2++) {
      float cv = cb[(size_t)c2 * (MB * D)];
#pragma unroll
      for (int tt = 0; tt < WT; tt++) acc[tt] += phi[tt][c2] * cv;
    }
    for (int tt = 0; tt < WT; tt++)
      wout[((size_t)(t0 + tt) * MB + b) * D + d] = acc[tt];
  }
}

// ---------------- K4/K5: fp32 tiled GEMM, 128x128 tile, BK=8, 256 threads, 8x8/thread
// C[m, n] = sum_k A[m,k]*B[k, n0+colOff+nn] + bias[n0+colOff+nn] + (wadd ? wadd[m*Nout+n] : 0)
__global__ __launch_bounds__(256) void gemm128(const float* __restrict__ A,
                                               const float* __restrict__ B,
                                               const float* __restrict__ bias,
                                               const float* __restrict__ wadd,
                                               float* __restrict__ C,
                                               int Kdim, int ldb, int Nout, int remapHalf) {
  __shared__ float As[8][128];
  __shared__ float Bs[8][128];
  const int bm = blockIdx.x, bn = blockIdx.y;
  const int tid = threadIdx.x;
  const int tm = (tid >> 4) << 3;
  const int tn = (tid & 15) << 3;
  const int colOff = (remapHalf && bn >= 4) ? 512 : 0;
  const int n0 = bn * 128;
  float acc[8][8];
#pragma unroll
  for (int i = 0; i < 8; i++)
#pragma unroll
    for (int j = 0; j < 8; j++) acc[i][j] = 0.f;
  const int ar = tid >> 1;
  const int ak = (tid & 1) << 2;
  const int bkr = tid >> 5;
  const int bc = (tid & 31) << 2;
  const float* Aptr = A + (size_t)(bm * 128 + ar) * Kdim + ak;
  const float* Bptr = B + (size_t)bkr * ldb + n0 + colOff + bc;
  for (int k0 = 0; k0 < Kdim; k0 += 8) {
    float4 a4 = *(const float4*)(Aptr + k0);
    float4 b4 = *(const float4*)(Bptr + (size_t)k0 * ldb);
    As[ak + 0][ar] = a4.x; As[ak + 1][ar] = a4.y; As[ak + 2][ar] = a4.z; As[ak + 3][ar] = a4.w;
    *(float4*)&Bs[bkr][bc] = b4;
    __syncthreads();
#pragma unroll
    for (int kk = 0; kk < 8; kk++) {
      float a8[8], b8[8];
      *(float4*)&a8[0] = *(const float4*)&As[kk][tm];
      *(float4*)&a8[4] = *(const float4*)&As[kk][tm + 4];
      *(float4*)&b8[0] = *(const float4*)&Bs[kk][tn];
      *(float4*)&b8[4] = *(const float4*)&Bs[kk][tn + 4];
#pragma unroll
      for (int i = 0; i < 8; i++)
#pragma unroll
        for (int j = 0; j < 8; j++) acc[i][j] += a8[i] * b8[j];
    }
    __syncthreads();
  }
  float bb8[8];
#pragma unroll
  for (int j = 0; j < 8; j++) bb8[j] = bias[n0 + colOff + tn + j];
#pragma unroll
  for (int i = 0; i < 8; i++) {
    int m = bm * 128 + tm + i;
    size_t co = (size_t)m * Nout + n0 + tn;
    float v[8];
#pragma unroll
    for (int j = 0; j < 8; j++) v[j] = acc[i][j] + bb8[j];
    if (wadd) {
      float4 w0 = *(const float4*)&wadd[co];
      float4 w1 = *(const float4*)&wadd[co + 4];
      v[0] += w0.x; v[1] += w0.y; v[2] += w0.z; v[3] += w0.w;
      v[4] += w1.x; v[5] += w1.y; v[6] += w1.z; v[7] += w1.w;
    }
    float4 o0 = make_float4(v[0], v[1], v[2], v[3]);
    float4 o1 = make_float4(v[4], v[5], v[6], v[7]);
    *(float4*)&C[co] = o0;
    *(float4*)&C[co + 4] = o1;
  }
}

// ---------------- K6: per-batch recurrence. One block per b, 512 threads. ----------------
// r = sigmoid(h @ WrT[j] + gate_r) ; h' = h + 1 + tanh((s*r) @ UT[j] + s)
__global__ __launch_bounds__(512) void recurrence_kernel(const float* __restrict__ F2,
                                                         const unsigned short* __restrict__ WrT,
                                                         const unsigned short* __restrict__ UT,
                                                         const float* __restrict__ gru_init,
                                                         float* __restrict__ hout) {
  int b = blockIdx.x;
  int j = threadIdx.x;
  __shared__ float h[D];
  __shared__ float sr[D];
  h[j] = gru_init[b * D + j];
  const unsigned short* wr = WrT + (size_t)j * D;
  const unsigned short* ut = UT + (size_t)j * D;
  __syncthreads();
  for (int t = 0; t < TS; t++) {
    const float* f2 = F2 + ((size_t)t * MB + b) * 1024;
    float s = f2[j];
    float g = f2[D + j];
    float acc = 0.f;
#pragma unroll 4
    for (int i = 0; i < D; i += 8) {
      uint4 wv = *(const uint4*)&wr[i];
      float4 h0 = *(const float4*)&h[i];
      float4 h1 = *(const float4*)&h[i + 4];
      acc += h0.x * bflo(wv.x) + h0.y * bfhi(wv.x)
           + h0.z * bflo(wv.y) + h0.w * bfhi(wv.y)
           + h1.x * bflo(wv.z) + h1.y * bfhi(wv.z)
           + h1.z * bflo(wv.w) + h1.w * bfhi(wv.w);
    }
    float r = 1.f / (1.f + expf(-(acc + g)));
    sr[j] = s * r;
    __syncthreads();
    float acc2 = 0.f;
#pragma unroll 4
    for (int i = 0; i < D; i += 8) {
      uint4 wv = *(const uint4*)&ut[i];
      float4 s0 = *(const float4*)&sr[i];
      float4 s1 = *(const float4*)&sr[i + 4];
      acc2 += s0.x * bflo(wv.x) + s0.y * bfhi(wv.x)
            + s0.z * bflo(wv.y) + s0.w * bfhi(wv.y)
            + s1.x * bflo(wv.z) + s1.y * bfhi(wv.z)
            + s1.z * bflo(wv.w) + s1.w * bfhi(wv.w);
    }
    float hn = h[j] + 1.f + tanhf(acc2 + s);
    h[j] = hn;
    hout[((size_t)t * MB + b) * D + j] = hn;
    __syncthreads();
  }
}

extern "C" void kernel_launch(void* const* d_in, const int* in_sizes, int n_in,
                              void* d_out, int out_size, void* d_ws, size_t ws_size,
                              hipStream_t stream) {
  const float* c_inp    = (const float*)d_in[0];
  const float* inp      = (const float*)d_in[1];
  const float* gru_init = (const float*)d_in[2];
  const float* att_init = (const float*)d_in[3];
  const float* Wa   = (const float*)d_in[4];
  const float* ba   = (const float*)d_in[5];
  const float* Wb   = (const float*)d_in[6];
  const float* bb   = (const float*)d_in[7];
  const float* Wk   = (const float*)d_in[8];
  const float* bk   = (const float*)d_in[9];
  const float* Wif  = (const float*)d_in[10];
  const float* bif  = (const float*)d_in[11];
  const float* Wfork= (const float*)d_in[12];
  const float* bfork= (const float*)d_in[13];
  const float* Wur  = (const float*)d_in[14];
  const float* U    = (const float*)d_in[15];

  float* out = (float*)d_out;
  float* hid  = out;
  float* attk = out + ATTK_OFF;
  float* attw = out + ATTW_OFF;

  char* ws = (char*)d_ws;
  unsigned short* WrT = (unsigned short*)(ws + WS_WRT);
  unsigned short* UT  = (unsigned short*)(ws + WS_UT);
  float* alpha = (float*)(ws + WS_ALPHA);
  float* beta  = (float*)(ws + WS_BETA);
  float* kinc  = (float*)(ws + WS_KINC);
  float* X     = (float*)(ws + WS_X);
  float* F2    = (float*)(ws + WS_F2);

  hipLaunchKernelGGL(prep_weights, dim3(1024), dim3(256), 0, stream, Wur, U, WrT, UT);
  hipLaunchKernelGGL(abk_kernel, dim3(TS * MB / ABK_ROWS), dim3(64), 0, stream,
                     inp, Wa, ba, Wb, bb, Wk, bk, alpha, beta, kinc);
  hipLaunchKernelGGL(cumsum_kernel, dim3((MB * KMIX + 255) / 256), dim3(256), 0, stream,
                     att_init, kinc, attk);
  hipLaunchKernelGGL(phi_w_kernel, dim3(MB * (TS / WT)), dim3(512), 0, stream,
                     c_inp, alpha, beta, attk, attw);
  // X = inp @ Wif + bif + w
  hipLaunchKernelGGL(gemm128, dim3(TS * MB / 128, D / 128), dim3(256), 0, stream,
                     inp, Wif, bif, attw, X, D, D, D, 0);
  // F2 = X @ Wfork[:, {0:512, 1024:1536}] + bfork[...]
  hipLaunchKernelGGL(gemm128, dim3(TS * MB / 128, 1024 / 128), dim3(256), 0, stream,
                     X, Wfork, bfork, (const float*)nullptr, F2, D, 3 * D, 1024, 1);
  hipLaunchKernelGGL(recurrence_kernel, dim3(MB), dim3(512), 0, stream,
                     F2, WrT, UT, gru_init, hid);
}

// Round 2
// 3694.505 us; speedup vs baseline: 2.1841x; 2.1841x over previous
//
#include <hip/hip_runtime.h>
#include <hip/hip_bf16.h>
#include <math.h>

#define TS   256
#define CTS  512
#define MB   64
#define D    512
#define KMIX 20

// d_out layout (floats): hiddens [TS][MB][D], att_k [TS][MB][KMIX], att_w [TS][MB][D]
#define HID_SIZE  (TS*MB*D)
#define ATTK_OFF  (HID_SIZE)
#define ATTW_OFF  (HID_SIZE + TS*MB*KMIX)

// ws layout (bytes):
//  WrPK (bf16 frag-packed reset half of Wur) @ 0        (524288)
//  UPK  (bf16 frag-packed U)                 @ 524288   (524288)
//  alpha @ 1048576, beta @ 2359296, kinc @ 3670016 (f32 TS*MB*K each)
//  X  (f32 TS*MB*D)    @ 5242880
//  F2 (f32 TS*MB*1024) @ 38797312   — [0:512]=state, [512:1024]=gate_r
#define WS_WRPK  0
#define WS_UPK   524288
#define WS_ALPHA 1048576
#define WS_BETA  2359296
#define WS_KINC  3670016
#define WS_X     5242880
#define WS_F2    38797312

typedef __attribute__((ext_vector_type(8))) short bf16x8;
typedef __attribute__((ext_vector_type(4))) float f32x4;

__device__ __forceinline__ unsigned short f2bf(float v) {
  __hip_bfloat16 h = __float2bfloat16(v);
  union { __hip_bfloat16 h; unsigned short u; } cvt; cvt.h = h;
  return cvt.u;
}

// ---------------- K0: pack recurrence weights into MFMA B-fragment order ----------------
// Fragment f = nt*16 + kt (nt: 16-col tile 0..31, kt: 32-k tile 0..15).
// Element (f, lane l, e): k = kt*32 + (l>>4)*8 + e ; n = nt*16 + (l&15).
// Stored at elem index (f*64 + l)*8 + e  → one bf16x8 (16B) per lane per frag.
__global__ __launch_bounds__(256) void pack_weights(const float* __restrict__ Wur,
                                                    const float* __restrict__ U,
                                                    unsigned short* __restrict__ WrPK,
                                                    unsigned short* __restrict__ UPK) {
  int idx = blockIdx.x * 256 + threadIdx.x;    // 512*512 = 262144 total
  int l = idx & 63;
  int e = (idx >> 6) & 7;
  int f = idx >> 9;
  int kt = f & 15, nt = f >> 4;
  int k = kt * 32 + ((l >> 4) << 3) + e;
  int n = (nt << 4) + (l & 15);
  int o = ((f * 64 + l) << 3) + e;
  WrPK[o] = f2bf(Wur[k * 1024 + 512 + n]);
  UPK[o]  = f2bf(U[k * 512 + n]);
}

// ---------------- K1: alpha = inp@Wa+ba (log domain), beta, kinc ----------------
#define ABK_ROWS 8
__global__ __launch_bounds__(64) void abk_kernel(const float* __restrict__ inp,
                                                 const float* __restrict__ Wa, const float* __restrict__ ba,
                                                 const float* __restrict__ Wb, const float* __restrict__ bb_,
                                                 const float* __restrict__ Wk, const float* __restrict__ bk,
                                                 float* __restrict__ alpha, float* __restrict__ beta,
                                                 float* __restrict__ kinc) {
  __shared__ float rows[ABK_ROWS][D];
  int tb0 = blockIdx.x * ABK_ROWS;
  for (int x = threadIdx.x; x < ABK_ROWS * D; x += 64)
    rows[x >> 9][x & 511] = inp[(size_t)tb0 * D + x];
  __syncthreads();
  int j = threadIdx.x;
  if (j >= 3 * KMIX) return;
  int wj = j % KMIX;
  int which = j / KMIX;
  const float* W = (which == 0) ? Wa : ((which == 1) ? Wb : Wk);
  const float* B = (which == 0) ? ba : ((which == 1) ? bb_ : bk);
  float acc[ABK_ROWS];
  float bias = B[wj];
#pragma unroll
  for (int r = 0; r < ABK_ROWS; r++) acc[r] = bias;
  for (int i = 0; i < D; i++) {
    float wv = W[i * KMIX + wj];
#pragma unroll
    for (int r = 0; r < ABK_ROWS; r++) acc[r] += rows[r][i] * wv;
  }
  for (int r = 0; r < ABK_ROWS; r++) {
    int tb = tb0 + r;
    float v = acc[r];
    if (which == 0) alpha[tb * KMIX + wj] = v;
    else if (which == 1) beta[tb * KMIX + wj] = expf(v);
    else kinc[tb * KMIX + wj] = expf(v);
  }
}

// ---------------- K2: k cumsum over t; writes att_k region of d_out ----------------
__global__ __launch_bounds__(256) void cumsum_kernel(const float* __restrict__ att_init,
                                                     const float* __restrict__ kinc,
                                                     float* __restrict__ kout) {
  int idx = blockIdx.x * 256 + threadIdx.x;
  if (idx >= MB * KMIX) return;
  float k = att_init[idx];
  for (int t = 0; t < TS; t++) {
    k += kinc[t * MB * KMIX + idx];
    kout[t * MB * KMIX + idx] = k;
  }
}

// ---------------- K3: phi + w GEMM; writes att_w region of d_out ----------------
#define WT 8
__global__ __launch_bounds__(512) void phi_w_kernel(const float* __restrict__ c_inp,
                                                    const float* __restrict__ alpha,
                                                    const float* __restrict__ beta,
                                                    const float* __restrict__ katt,
                                                    float* __restrict__ wout) {
  int b  = blockIdx.x / (TS / WT);
  int t0 = (blockIdx.x % (TS / WT)) * WT;
  __shared__ float phi[WT][CTS];
  __shared__ float pa[WT][KMIX], pb[WT][KMIX], pk[WT][KMIX];
  for (int x = threadIdx.x; x < WT * KMIX; x += 512) {
    int tt = x / KMIX, j = x % KMIX;
    int tb = (t0 + tt) * MB + b;
    pa[tt][j] = alpha[tb * KMIX + j];
    pb[tt][j] = beta[tb * KMIX + j];
    pk[tt][j] = katt[tb * KMIX + j];
  }
  __syncthreads();
  {
    int c = threadIdx.x;
    float fc = (float)c;
#pragma unroll
    for (int tt = 0; tt < WT; tt++) {
      float s = 0.f;
#pragma unroll
      for (int j = 0; j < KMIX; j++) {
        float dd = pk[tt][j] - fc;
        s += expf(pa[tt][j] - pb[tt][j] * dd * dd);
      }
      phi[tt][c] = s;
    }
  }
  __syncthreads();
  {
    int d = threadIdx.x;
    float acc[WT];
#pragma unroll
    for (int tt = 0; tt < WT; tt++) acc[tt] = 0.f;
    const float* cb = c_inp + (size_t)b * D + d;
    for (int c2 = 0; c2 < CTS; c2++) {
      float cv = cb[(size_t)c2 * (MB * D)];
#pragma unroll
      for (int tt = 0; tt < WT; tt++) acc[tt] += phi[tt][c2] * cv;
    }
    for (int tt = 0; tt < WT; tt++)
      wout[((size_t)(t0 + tt) * MB + b) * D + d] = acc[tt];
  }
}

// ---------------- K4/K5: fp32 tiled GEMM, 128x128 tile ----------------
__global__ __launch_bounds__(256) void gemm128(const float* __restrict__ A,
                                               const float* __restrict__ B,
                                               const float* __restrict__ bias,
                                               const float* __restrict__ wadd,
                                               float* __restrict__ C,
                                               int Kdim, int ldb, int Nout, int remapHalf) {
  __shared__ float As[8][128];
  __shared__ float Bs[8][128];
  const int bm = blockIdx.x, bn = blockIdx.y;
  const int tid = threadIdx.x;
  const int tm = (tid >> 4) << 3;
  const int tn = (tid & 15) << 3;
  const int colOff = (remapHalf && bn >= 4) ? 512 : 0;
  const int n0 = bn * 128;
  float acc[8][8];
#pragma unroll
  for (int i = 0; i < 8; i++)
#pragma unroll
    for (int j = 0; j < 8; j++) acc[i][j] = 0.f;
  const int ar = tid >> 1;
  const int ak = (tid & 1) << 2;
  const int bkr = tid >> 5;
  const int bc = (tid & 31) << 2;
  const float* Aptr = A + (size_t)(bm * 128 + ar) * Kdim + ak;
  const float* Bptr = B + (size_t)bkr * ldb + n0 + colOff + bc;
  for (int k0 = 0; k0 < Kdim; k0 += 8) {
    float4 a4 = *(const float4*)(Aptr + k0);
    float4 b4 = *(const float4*)(Bptr + (size_t)k0 * ldb);
    As[ak + 0][ar] = a4.x; As[ak + 1][ar] = a4.y; As[ak + 2][ar] = a4.z; As[ak + 3][ar] = a4.w;
    *(float4*)&Bs[bkr][bc] = b4;
    __syncthreads();
#pragma unroll
    for (int kk = 0; kk < 8; kk++) {
      float a8[8], b8[8];
      *(float4*)&a8[0] = *(const float4*)&As[kk][tm];
      *(float4*)&a8[4] = *(const float4*)&As[kk][tm + 4];
      *(float4*)&b8[0] = *(const float4*)&Bs[kk][tn];
      *(float4*)&b8[4] = *(const float4*)&Bs[kk][tn + 4];
#pragma unroll
      for (int i = 0; i < 8; i++)
#pragma unroll
        for (int j = 0; j < 8; j++) acc[i][j] += a8[i] * b8[j];
    }
    __syncthreads();
  }
  float bb8[8];
#pragma unroll
  for (int j = 0; j < 8; j++) bb8[j] = bias[n0 + colOff + tn + j];
#pragma unroll
  for (int i = 0; i < 8; i++) {
    int m = bm * 128 + tm + i;
    size_t co = (size_t)m * Nout + n0 + tn;
    float v[8];
#pragma unroll
    for (int j = 0; j < 8; j++) v[j] = acc[i][j] + bb8[j];
    if (wadd) {
      float4 w0 = *(const float4*)&wadd[co];
      float4 w1 = *(const float4*)&wadd[co + 4];
      v[0] += w0.x; v[1] += w0.y; v[2] += w0.z; v[3] += w0.w;
      v[4] += w1.x; v[5] += w1.y; v[6] += w1.z; v[7] += w1.w;
    }
    *(float4*)&C[co]     = make_float4(v[0], v[1], v[2], v[3]);
    *(float4*)&C[co + 4] = make_float4(v[4], v[5], v[6], v[7]);
  }
}

// ---------------- K6: MFMA recurrence. 4 blocks x 512 threads, 16 batches/block ----------------
// Per step: C1 = h_bf @ Wr  (16x512 @ 512x512); r = sigmoid(C1+g); sr = s*r;
//           C2 = sr_bf @ U ; h += 1 + tanh(C2 + s).
// h fp32 master lives in C/D-layout registers; bf16 copy in XOR-swizzled LDS for A-frags.
// Swizzle: elem offset for (m, j) = m*512 + ((j>>3 ^ (m&7))<<3) + (j&7)  (16B-group XOR).

__device__ __forceinline__ void lds_wr_bf(unsigned short* buf, int m, int j, float v) {
  int off = (m << 9) + ((((j >> 3) ^ (m & 7))) << 3) + (j & 7);
  buf[off] = f2bf(v);
}

__device__ __forceinline__ bf16x8 lds_rd_frag(const unsigned short* buf, int m, int g) {
  return *(const bf16x8*)(buf + (m << 9) + ((g ^ (m & 7)) << 3));
}

__global__ __launch_bounds__(512, 2) void recurrence_mfma(
    const float* __restrict__ F2,
    const bf16x8* __restrict__ WrPK,
    const bf16x8* __restrict__ UPK,
    const float* __restrict__ gru_init,
    float* __restrict__ hout) {
  __shared__ unsigned short hbf[16 * 512];
  __shared__ unsigned short srbf[16 * 512];
  const int tid  = threadIdx.x;
  const int wave = tid >> 6;
  const int lane = tid & 63;
  const int lg = lane >> 4;        // lane k/row group
  const int ln = lane & 15;        // n (col) / A-row index
  const int b0 = blockIdx.x * 16;

  float hreg[4][4];                // [q: ntile][r: C reg] -> (m = lg*4+r, j = (wave*4+q)*16+ln)
#pragma unroll
  for (int q = 0; q < 4; q++) {
    int j = ((wave * 4 + q) << 4) + ln;
#pragma unroll
    for (int r = 0; r < 4; r++) {
      int m = (lg << 2) + r;
      float v = gru_init[(b0 + m) * D + j];
      hreg[q][r] = v;
      lds_wr_bf(hbf, m, j, v);
    }
  }
  __syncthreads();

  const f32x4 zero4 = {0.f, 0.f, 0.f, 0.f};
  for (int t = 0; t < TS; t++) {
    const float* f2 = F2 + ((size_t)t * MB + b0) * 1024;
    float sreg[4][4], greg[4][4];
#pragma unroll
    for (int q = 0; q < 4; q++) {
      int j = ((wave * 4 + q) << 4) + ln;
#pragma unroll
      for (int r = 0; r < 4; r++) {
        int m = (lg << 2) + r;
        sreg[q][r] = f2[m * 1024 + j];
        greg[q][r] = f2[m * 1024 + 512 + j];
      }
    }
    // --- matvec 1: h @ Wr ---
    f32x4 c1[4] = {zero4, zero4, zero4, zero4};
#pragma unroll 4
    for (int kt = 0; kt < 16; kt++) {
      bf16x8 a = lds_rd_frag(hbf, ln, (kt << 2) + lg);
#pragma unroll
      for (int q = 0; q < 4; q++) {
        bf16x8 bfr = WrPK[(((wave * 4 + q) * 16 + kt) << 6) + lane];
        c1[q] = __builtin_amdgcn_mfma_f32_16x16x32_bf16(a, bfr, c1[q], 0, 0, 0);
      }
    }
    // --- epilogue 1: r = sigmoid(c1+g), sr = s*r ---
#pragma unroll
    for (int q = 0; q < 4; q++) {
      int j = ((wave * 4 + q) << 4) + ln;
#pragma unroll
      for (int r = 0; r < 4; r++) {
        int m = (lg << 2) + r;
        float rr = 1.f / (1.f + expf(-(c1[q][r] + greg[q][r])));
        lds_wr_bf(srbf, m, j, sreg[q][r] * rr);
      }
    }
    __syncthreads();
    // --- matvec 2: sr @ U ---
    f32x4 c2[4] = {zero4, zero4, zero4, zero4};
#pragma unroll 4
    for (int kt = 0; kt < 16; kt++) {
      bf16x8 a = lds_rd_frag(srbf, ln, (kt << 2) + lg);
#pragma unroll
      for (int q = 0; q < 4; q++) {
        bf16x8 bfr = UPK[(((wave * 4 + q) * 16 + kt) << 6) + lane];
        c2[q] = __builtin_amdgcn_mfma_f32_16x16x32_bf16(a, bfr, c2[q], 0, 0, 0);
      }
    }
    // --- epilogue 2: h += 1 + tanh(c2 + s); write hout + hbf ---
#pragma unroll
    for (int q = 0; q < 4; q++) {
      int j = ((wave * 4 + q) << 4) + ln;
#pragma unroll
      for (int r = 0; r < 4; r++) {
        int m = (lg << 2) + r;
        float hn = hreg[q][r] + 1.f + tanhf(c2[q][r] + sreg[q][r]);
        hreg[q][r] = hn;
        hout[((size_t)t * MB + (b0 + m)) * D + j] = hn;
        lds_wr_bf(hbf, m, j, hn);
      }
    }
    __syncthreads();
  }
}

extern "C" void kernel_launch(void* const* d_in, const int* in_sizes, int n_in,
                              void* d_out, int out_size, void* d_ws, size_t ws_size,
                              hipStream_t stream) {
  const float* c_inp    = (const float*)d_in[0];
  const float* inp      = (const float*)d_in[1];
  const float* gru_init = (const float*)d_in[2];
  const float* att_init = (const float*)d_in[3];
  const float* Wa   = (const float*)d_in[4];
  const float* ba   = (const float*)d_in[5];
  const float* Wb   = (const float*)d_in[6];
  const float* bb   = (const float*)d_in[7];
  const float* Wk   = (const float*)d_in[8];
  const float* bk   = (const float*)d_in[9];
  const float* Wif  = (const float*)d_in[10];
  const float* bif  = (const float*)d_in[11];
  const float* Wfork= (const float*)d_in[12];
  const float* bfork= (const float*)d_in[13];
  const float* Wur  = (const float*)d_in[14];
  const float* U    = (const float*)d_in[15];

  float* out = (float*)d_out;
  float* hid  = out;
  float* attk = out + ATTK_OFF;
  float* attw = out + ATTW_OFF;

  char* ws = (char*)d_ws;
  unsigned short* WrPK = (unsigned short*)(ws + WS_WRPK);
  unsigned short* UPK  = (unsigned short*)(ws + WS_UPK);
  float* alpha = (float*)(ws + WS_ALPHA);
  float* beta  = (float*)(ws + WS_BETA);
  float* kinc  = (float*)(ws + WS_KINC);
  float* X     = (float*)(ws + WS_X);
  float* F2    = (float*)(ws + WS_F2);

  hipLaunchKernelGGL(pack_weights, dim3(1024), dim3(256), 0, stream, Wur, U, WrPK, UPK);
  hipLaunchKernelGGL(abk_kernel, dim3(TS * MB / ABK_ROWS), dim3(64), 0, stream,
                     inp, Wa, ba, Wb, bb, Wk, bk, alpha, beta, kinc);
  hipLaunchKernelGGL(cumsum_kernel, dim3((MB * KMIX + 255) / 256), dim3(256), 0, stream,
                     att_init, kinc, attk);
  hipLaunchKernelGGL(phi_w_kernel, dim3(MB * (TS / WT)), dim3(512), 0, stream,
                     c_inp, alpha, beta, attk, attw);
  hipLaunchKernelGGL(gemm128, dim3(TS * MB / 128, D / 128), dim3(256), 0, stream,
                     inp, Wif, bif, attw, X, D, D, D, 0);
  hipLaunchKernelGGL(gemm128, dim3(TS * MB / 128, 1024 / 128), dim3(256), 0, stream,
                     X, Wfork, bfork, (const float*)nullptr, F2, D, 3 * D, 1024, 1);
  hipLaunchKernelGGL(recurrence_mfma, dim3(4), dim3(512), 0, stream,
                     F2, (const bf16x8*)WrPK, (const bf16x8*)UPK, gru_init, hid);
}